// Round 1
// baseline (1433.906 us; speedup 1.0000x reference)
//
#include <hip/hip_runtime.h>

#define N_NODES 100000
#define N_EDGES 1600000
#define D_FEAT 64

// 16 threads per edge; each thread handles one float4 chunk (4 feats).
// Edge scalars (src/dst/val) are read redundantly by the 16 lanes -> cache broadcast.
__global__ void spmm_atomic_kernel(const float* __restrict__ x,
                                   const float* __restrict__ edge_val,
                                   const int* __restrict__ edge_src,
                                   const int* __restrict__ edge_dst,
                                   float* __restrict__ out) {
    const int tid = blockIdx.x * blockDim.x + threadIdx.x;
    const int e = tid >> 4;        // edge index
    const int c = tid & 15;        // float4 chunk within the 64-feat row
    if (e >= N_EDGES) return;

    const int s = edge_src[e];
    const int d = edge_dst[e];
    const float v = edge_val[e];

    const float4 m = ((const float4*)(x + (size_t)s * D_FEAT))[c];
    float* o = out + (size_t)d * D_FEAT + (size_t)c * 4;

    atomicAdd(o + 0, v * m.x);
    atomicAdd(o + 1, v * m.y);
    atomicAdd(o + 2, v * m.z);
    atomicAdd(o + 3, v * m.w);
}

extern "C" void kernel_launch(void* const* d_in, const int* in_sizes, int n_in,
                              void* d_out, int out_size, void* d_ws, size_t ws_size,
                              hipStream_t stream) {
    const float* x        = (const float*)d_in[0];
    const float* edge_val = (const float*)d_in[1];
    const int*   edge_src = (const int*)d_in[2];
    const int*   edge_dst = (const int*)d_in[3];
    float* out = (float*)d_out;

    // d_out is poisoned (0xAA) before every timed launch -> zero it ourselves.
    hipMemsetAsync(out, 0, (size_t)out_size * sizeof(float), stream);

    const int threads_total = N_EDGES * 16;
    const int block = 256;
    const int grid = (threads_total + block - 1) / block;
    spmm_atomic_kernel<<<grid, block, 0, stream>>>(x, edge_val, edge_src, edge_dst, out);
}

// Round 2
// 345.751 us; speedup vs baseline: 4.1472x; 4.1472x over previous
//
#include <hip/hip_runtime.h>

#define N_NODES 100000
#define N_EDGES 1600000
#define D_FEAT 64
#define SCAN_B 1024
#define N_SCAN_BLOCKS ((N_NODES + SCAN_B - 1) / SCAN_B)   // 98

// ---------- Phase 1: degree histogram ----------
__global__ void hist_kernel(const int* __restrict__ dst, int* __restrict__ deg) {
    int e = blockIdx.x * blockDim.x + threadIdx.x;
    if (e < N_EDGES) atomicAdd(&deg[dst[e]], 1);
}

// ---------- Phase 2a: per-block exclusive scan of degrees ----------
__global__ void scan_block_kernel(const int* __restrict__ deg,
                                  int* __restrict__ offs,
                                  int* __restrict__ sums) {
    __shared__ int sh[SCAN_B];
    const int gid = blockIdx.x * SCAN_B + threadIdx.x;
    const int v = (gid < N_NODES) ? deg[gid] : 0;
    sh[threadIdx.x] = v;
    __syncthreads();
    // Hillis-Steele inclusive scan
    for (int off = 1; off < SCAN_B; off <<= 1) {
        int t = (threadIdx.x >= off) ? sh[threadIdx.x - off] : 0;
        __syncthreads();
        sh[threadIdx.x] += t;
        __syncthreads();
    }
    if (gid < N_NODES) offs[gid] = sh[threadIdx.x] - v;     // exclusive
    if (threadIdx.x == SCAN_B - 1) sums[blockIdx.x] = sh[threadIdx.x];
}

// ---------- Phase 2b: exclusive scan of the 98 block sums ----------
__global__ void scan_sums_kernel(int* __restrict__ sums) {
    __shared__ int sh[128];
    const int v = (threadIdx.x < N_SCAN_BLOCKS) ? sums[threadIdx.x] : 0;
    sh[threadIdx.x] = v;
    __syncthreads();
    for (int off = 1; off < 128; off <<= 1) {
        int t = (threadIdx.x >= off) ? sh[threadIdx.x - off] : 0;
        __syncthreads();
        sh[threadIdx.x] += t;
        __syncthreads();
    }
    if (threadIdx.x < N_SCAN_BLOCKS) sums[threadIdx.x] = sh[threadIdx.x] - v;
}

// ---------- Phase 2c: add block offsets; init cursor; cap offs ----------
__global__ void scan_add_kernel(int* __restrict__ offs,
                                const int* __restrict__ sums,
                                int* __restrict__ cursor) {
    const int gid = blockIdx.x * blockDim.x + threadIdx.x;
    if (gid < N_NODES) {
        const int o = offs[gid] + sums[gid / SCAN_B];
        offs[gid] = o;
        cursor[gid] = o;
    }
    if (gid == 0) offs[N_NODES] = N_EDGES;
}

// ---------- Phase 3: scatter edges into CSR slots ----------
__global__ void scatter_kernel(const int* __restrict__ src,
                               const int* __restrict__ dst,
                               const float* __restrict__ val,
                               int* __restrict__ cursor,
                               int* __restrict__ csr_src,
                               float* __restrict__ csr_val) {
    const int e = blockIdx.x * blockDim.x + threadIdx.x;
    if (e < N_EDGES) {
        const int pos = atomicAdd(&cursor[dst[e]], 1);
        csr_src[pos] = src[e];
        csr_val[pos] = val[e];
    }
}

// ---------- Phase 4: SpMM — 16 lanes per row, register accumulation ----------
__global__ void spmm_csr_kernel(const float* __restrict__ x,
                                const int* __restrict__ offs,
                                const int* __restrict__ csr_src,
                                const float* __restrict__ csr_val,
                                float* __restrict__ out) {
    const int tid = blockIdx.x * blockDim.x + threadIdx.x;
    const int row = tid >> 4;
    const int c = tid & 15;          // float4 chunk of the 64-feat row
    if (row >= N_NODES) return;
    const int beg = offs[row];
    const int end = offs[row + 1];
    float4 acc = {0.f, 0.f, 0.f, 0.f};
    for (int j = beg; j < end; ++j) {
        const int s = csr_src[j];        // same addr across 16 lanes -> broadcast
        const float v = csr_val[j];
        const float4 m = ((const float4*)(x + (size_t)s * D_FEAT))[c];
        acc.x += v * m.x;
        acc.y += v * m.y;
        acc.z += v * m.z;
        acc.w += v * m.w;
    }
    ((float4*)(out + (size_t)row * D_FEAT))[c] = acc;   // single non-atomic write
}

extern "C" void kernel_launch(void* const* d_in, const int* in_sizes, int n_in,
                              void* d_out, int out_size, void* d_ws, size_t ws_size,
                              hipStream_t stream) {
    const float* x        = (const float*)d_in[0];
    const float* edge_val = (const float*)d_in[1];
    const int*   edge_src = (const int*)d_in[2];
    const int*   edge_dst = (const int*)d_in[3];
    float* out = (float*)d_out;

    // Workspace layout (all 4-byte elems, ~14 MB total)
    int* ws       = (int*)d_ws;
    int* deg      = ws;                        // N
    int* offs     = deg + N_NODES;             // N+1
    int* cursor   = offs + N_NODES + 1;        // N
    int* sums     = cursor + N_NODES;          // 128
    int* csr_src  = sums + 128;                // E
    float* csr_val = (float*)(csr_src + N_EDGES); // E

    // d_ws is re-poisoned each launch: zero the histogram counters.
    hipMemsetAsync(deg, 0, N_NODES * sizeof(int), stream);

    const int B = 256;
    const int gridE = (N_EDGES + B - 1) / B;          // 6250
    const int gridN = (N_NODES + B - 1) / B;          // 391
    const int gridRow = (N_NODES * 16 + B - 1) / B;   // 6250

    hist_kernel      <<<gridE, B, 0, stream>>>(edge_dst, deg);
    scan_block_kernel<<<N_SCAN_BLOCKS, SCAN_B, 0, stream>>>(deg, offs, sums);
    scan_sums_kernel <<<1, 128, 0, stream>>>(sums);
    scan_add_kernel  <<<gridN, B, 0, stream>>>(offs, sums, cursor);
    scatter_kernel   <<<gridE, B, 0, stream>>>(edge_src, edge_dst, edge_val,
                                               cursor, csr_src, csr_val);
    spmm_csr_kernel  <<<gridRow, B, 0, stream>>>(x, offs, csr_src, csr_val, out);
}

// Round 3
// 337.185 us; speedup vs baseline: 4.2526x; 1.0254x over previous
//
#include <hip/hip_runtime.h>

#define N_NODES 100000
#define N_EDGES 1600000
#define D_FEAT 64
#define SCAN_B 1024
#define N_SCAN_BLOCKS ((N_NODES + SCAN_B - 1) / SCAN_B)   // 98

// ---------- Phase 1: degree histogram ----------
__global__ void hist_kernel(const int* __restrict__ dst, int* __restrict__ deg) {
    int e = blockIdx.x * blockDim.x + threadIdx.x;
    if (e < N_EDGES) atomicAdd(&deg[dst[e]], 1);
}

// ---------- Phase 2a: per-block exclusive scan of degrees ----------
__global__ void scan_block_kernel(const int* __restrict__ deg,
                                  int* __restrict__ offs,
                                  int* __restrict__ sums) {
    __shared__ int sh[SCAN_B];
    const int gid = blockIdx.x * SCAN_B + threadIdx.x;
    const int v = (gid < N_NODES) ? deg[gid] : 0;
    sh[threadIdx.x] = v;
    __syncthreads();
    for (int off = 1; off < SCAN_B; off <<= 1) {
        int t = (threadIdx.x >= off) ? sh[threadIdx.x - off] : 0;
        __syncthreads();
        sh[threadIdx.x] += t;
        __syncthreads();
    }
    if (gid < N_NODES) offs[gid] = sh[threadIdx.x] - v;     // exclusive
    if (threadIdx.x == SCAN_B - 1) sums[blockIdx.x] = sh[threadIdx.x];
}

// ---------- Phase 2b: exclusive scan of the 98 block sums ----------
__global__ void scan_sums_kernel(int* __restrict__ sums) {
    __shared__ int sh[128];
    const int v = (threadIdx.x < N_SCAN_BLOCKS) ? sums[threadIdx.x] : 0;
    sh[threadIdx.x] = v;
    __syncthreads();
    for (int off = 1; off < 128; off <<= 1) {
        int t = (threadIdx.x >= off) ? sh[threadIdx.x - off] : 0;
        __syncthreads();
        sh[threadIdx.x] += t;
        __syncthreads();
    }
    if (threadIdx.x < N_SCAN_BLOCKS) sums[threadIdx.x] = sh[threadIdx.x] - v;
}

// ---------- Phase 2c: add block offsets; init cursor; cap offs ----------
__global__ void scan_add_kernel(int* __restrict__ offs,
                                const int* __restrict__ sums,
                                int* __restrict__ cursor) {
    const int gid = blockIdx.x * blockDim.x + threadIdx.x;
    if (gid < N_NODES) {
        const int o = offs[gid] + sums[gid / SCAN_B];
        offs[gid] = o;
        cursor[gid] = o;
    }
    if (gid == 0) offs[N_NODES] = N_EDGES;
}

// ---------- Phase 3: scatter edges into CSR slots (packed 8B payload) ----------
__global__ void scatter_kernel(const int* __restrict__ src,
                               const int* __restrict__ dst,
                               const float* __restrict__ val,
                               int* __restrict__ cursor,
                               int2* __restrict__ csr) {
    const int e = blockIdx.x * blockDim.x + threadIdx.x;
    if (e < N_EDGES) {
        const int pos = atomicAdd(&cursor[dst[e]], 1);
        csr[pos] = make_int2(src[e], __float_as_int(val[e]));  // one 8B store
    }
}

// ---------- Phase 4: SpMM — 16 lanes per row, register accumulation ----------
__global__ void spmm_csr_kernel(const float* __restrict__ x,
                                const int* __restrict__ offs,
                                const int2* __restrict__ csr,
                                float* __restrict__ out) {
    const int tid = blockIdx.x * blockDim.x + threadIdx.x;
    const int row = tid >> 4;
    const int c = tid & 15;          // float4 chunk of the 64-feat row
    if (row >= N_NODES) return;
    const int beg = offs[row];
    const int end = offs[row + 1];
    float4 acc = {0.f, 0.f, 0.f, 0.f};
    for (int j = beg; j < end; ++j) {
        const int2 pv = csr[j];          // same addr across 16 lanes -> broadcast
        const int s = pv.x;
        const float v = __int_as_float(pv.y);
        const float4 m = ((const float4*)(x + (size_t)s * D_FEAT))[c];
        acc.x += v * m.x;
        acc.y += v * m.y;
        acc.z += v * m.z;
        acc.w += v * m.w;
    }
    ((float4*)(out + (size_t)row * D_FEAT))[c] = acc;   // single non-atomic write
}

extern "C" void kernel_launch(void* const* d_in, const int* in_sizes, int n_in,
                              void* d_out, int out_size, void* d_ws, size_t ws_size,
                              hipStream_t stream) {
    const float* x        = (const float*)d_in[0];
    const float* edge_val = (const float*)d_in[1];
    const int*   edge_src = (const int*)d_in[2];
    const int*   edge_dst = (const int*)d_in[3];
    float* out = (float*)d_out;

    // Workspace layout (ints), ~14 MB total
    int* ws     = (int*)d_ws;
    int* deg    = ws;                        // N
    int* offs   = deg + N_NODES;             // N+1
    int* cursor = offs + N_NODES + 1;        // N
    int* sums   = cursor + N_NODES;          // 128
    size_t used = (size_t)3 * N_NODES + 1 + 128;
    used = (used + 1) & ~(size_t)1;          // 8-byte align for int2
    int2* csr   = (int2*)(ws + used);        // E entries

    // d_ws is re-poisoned each launch: zero the histogram counters.
    hipMemsetAsync(deg, 0, N_NODES * sizeof(int), stream);

    const int B = 256;
    const int gridE = (N_EDGES + B - 1) / B;          // 6250
    const int gridN = (N_NODES + B - 1) / B;          // 391
    const int gridRow = (N_NODES * 16 + B - 1) / B;   // 6250

    hist_kernel      <<<gridE, B, 0, stream>>>(edge_dst, deg);
    scan_block_kernel<<<N_SCAN_BLOCKS, SCAN_B, 0, stream>>>(deg, offs, sums);
    scan_sums_kernel <<<1, 128, 0, stream>>>(sums);
    scan_add_kernel  <<<gridN, B, 0, stream>>>(offs, sums, cursor);
    scatter_kernel   <<<gridE, B, 0, stream>>>(edge_src, edge_dst, edge_val,
                                               cursor, csr);
    spmm_csr_kernel  <<<gridRow, B, 0, stream>>>(x, offs, csr, out);
}